// Round 7
// baseline (150.751 us; speedup 1.0000x reference)
//
#include <hip/hip_runtime.h>

#define BATCH 8192
#define INC   512
#define OUTC  512
#define NB    8
#define KDIM  (INC * NB)   // 4096

#define BM 64
#define BN 128
#define BK 64
#define KSPLIT 2
#define THREADS 256
#define LDA 72             // A row stride in shorts (64 + 8 pad), 144 B

typedef __attribute__((ext_vector_type(8))) short bf16x8;
typedef __attribute__((ext_vector_type(4))) float f32x4;
typedef __attribute__((ext_vector_type(4))) int   i32x4;

// truncate-pack two fp32 into two bf16 (lo -> low 16 bits) in one v_perm_b32
static __device__ __forceinline__ unsigned int pk2(float lo, float hi) {
    return __builtin_amdgcn_perm(__builtin_bit_cast(unsigned int, hi),
                                 __builtin_bit_cast(unsigned int, lo),
                                 0x07060302u);
}

// ---- prepass: W fp32 -> bf16 (RNE) into workspace; also zero Y for the
//      split-K atomic accumulation. ----
__global__ __launch_bounds__(256)
void w_prepass(const float* __restrict__ W, unsigned short* __restrict__ Wb,
               float* __restrict__ Y) {
    const int gid  = blockIdx.x * 256 + threadIdx.x;   // 0..262143
    const int base = gid * 8;
    const float4 a = *(const float4*)(W + base);
    const float4 b = *(const float4*)(W + base + 4);
    const float v[8] = {a.x, a.y, a.z, a.w, b.x, b.y, b.z, b.w};
    unsigned int r[8];
#pragma unroll
    for (int i = 0; i < 8; ++i) {
        unsigned int t = __builtin_bit_cast(unsigned int, v[i]);
        t += 0x7FFFu + ((t >> 16) & 1u);   // round-to-nearest-even
        r[i] = t >> 16;
    }
    i32x4 out = {(int)(r[0] | (r[1] << 16)), (int)(r[2] | (r[3] << 16)),
                 (int)(r[4] | (r[5] << 16)), (int)(r[6] | (r[7] << 16))};
    *(i32x4*)(Wb + base) = out;

    float4* yp = (float4*)Y + (size_t)gid * 4;
    const float4 z = {0.f, 0.f, 0.f, 0.f};
#pragma unroll
    for (int i = 0; i < 4; ++i) yp[i] = z;
}

// Round 7 = R2 (the measured-best structure, 59us) + two surgical changes:
//  1. stage_A (basis VALU/trans) moved INSIDE the MFMA phase, between the
//     ks=0 and ks=1 MFMA batches, no sched fences -> compiler interleaves
//     VALU with MFMA (separate pipes). All prior rounds kept basis and
//     MFMA in different barrier phases = serialization (m196 anti-pattern).
//  2. split-K=2 -> 1024 blocks -> 3 blocks/CU (LDS 51.2KB fits 3) =
//     12 waves/CU; R2's 512-block grid capped residency at 2 although LDS
//     allowed 3. Atomic f32 epilogue (R4/R6-verified), Y zeroed in prepass.
//
// Cadence (unchanged from R2): double buffer, per step vm ops =
// [x float2, DMA x4] = 5; "s_waitcnt vmcnt(5) lgkmcnt(0)" before barrier#1
// drains the PREVIOUS step's DMA (one full step of cover; W is 4MB bf16 =
// L2-resident) while this step's 5 stay in flight. lgkmcnt(0) also fences
// every wave's own ds_reads/ds_writes before any buffer flip (WAR-safe).
//
// B LDS layout (swizzled): element (row 0..127, kblk 0..7) at short offset
// row*64 + (kblk ^ (row & 7)) * 8; DMA permutes the GLOBAL k-block.

template <bool DMA, bool SPLIT>
__global__ __launch_bounds__(THREADS, 3)
void tanh_basis_fused_gemm(const float* __restrict__ X,    // (BATCH, INC)
                           const void*  __restrict__ Wsrc, // (OUTC, KDIM)
                           const float* __restrict__ CEN,  // (INC, NB) rows identical
                           const float* __restrict__ SLP,  // (INC, NB) rows identical
                           float* __restrict__ Y)          // (BATCH, OUTC)
{
    __shared__ short As[2][BM][LDA];   // 2 *  9216 B
    __shared__ short Bs[2][BN * BK];   // 2 * 16384 B   (total 51200 -> 3 blk/CU)

    const int tid  = threadIdx.x;
    const int lane = tid & 63;
    const int wave = tid >> 6;     // 0..3
    const int wm   = wave & 1;     // m-wave: rows of 32
    const int wn   = wave >> 1;    // n-wave: cols of 64

    const int b0 = blockIdx.x * BM;
    const int j0 = blockIdx.y * BN;
    constexpr int NKTB = SPLIT ? (KDIM / BK / KSPLIT) : (KDIM / BK);  // 32 / 64
    const int kt0 = SPLIT ? blockIdx.z * NKTB : 0;

    // basis: s_m(x) = 1/(1 + exp2(g2*(c_m - x))), g2 = 2*gamma*log2(e)
    const float L2E = 1.4426950408889634f;
    const float g2  = 2.0f * SLP[0] * L2E;
    const float pc  = -g2;
    const float q0  = g2 * CEN[0];
    const float R   = __builtin_amdgcn_exp2f(g2 * (CEN[1] - CEN[0]));

    // A staging role: thread -> (row, 2 consecutive i-slots of the 8-wide slab)
    const int arow = tid >> 2;          // 0..63
    const int acol = (tid & 3) * 2;     // 0,2,4,6
    const float* xp = X + (size_t)(b0 + arow) * INC + acol;
    // x for ABSOLUTE k-tile tt: *(const float2*)(xp + tt*NB)

    f32x4 acc[2][4];
#pragma unroll
    for (int i = 0; i < 2; ++i)
#pragma unroll
        for (int j = 0; j < 4; ++j)
            acc[i][j] = (f32x4){0.f, 0.f, 0.f, 0.f};

    // fragment read offsets (within one buffer) — proven R2 layout
    const int rl = lane & 15;
    const int h  = lane >> 4;                        // 0..3
    const int aoff  = (wm * 32 + rl) * LDA + h * 8;
    const int brow  = wn * 64 + rl;
    const int low3  = lane & 7;                      // == brow & 7
    const int boff0 = brow * BK + ((h)     ^ low3) * 8;  // ks=0
    const int boff1 = brow * BK + ((4 + h) ^ low3) * 8;  // ks=1

    // DMA global-side swizzle (per-lane, hoisted out of k-loop)
    const int dma_r    = lane >> 3;                  // row within 8-row chunk
    const int dma_kblk = (lane & 7) ^ dma_r;         // permuted k-block

    auto stage_B = [&](int ktA, short* bs) {         // ktA ABSOLUTE k-tile
        if constexpr (DMA) {
            const unsigned short* Wb = (const unsigned short*)Wsrc;
#pragma unroll
            for (int q = 0; q < 4; ++q) {
                const int cc = wave * 4 + q;   // 1 KB chunk id, wave-uniform
                const unsigned short* gp = Wb
                    + (size_t)(j0 + cc * 8 + dma_r) * KDIM
                    + ktA * BK + dma_kblk * 8;
                __builtin_amdgcn_global_load_lds(
                    (const __attribute__((address_space(1))) void*)gp,
                    (__attribute__((address_space(3))) void*)(bs + cc * 512),
                    16, 0, 0);
            }
        } else {
            const float* Wf = (const float*)Wsrc;
            const int frow = tid >> 1;     // 0..127
            const int fkh  = tid & 1;      // which 32-float half
            const float* wp = Wf + (size_t)(j0 + frow) * KDIM + ktA * BK + fkh * 32;
            float4 cv[8];
#pragma unroll
            for (int q = 0; q < 8; ++q) cv[q] = ((const float4*)wp)[q];
#pragma unroll
            for (int kb = 0; kb < 4; ++kb) {
                const int kblk = fkh * 4 + kb;
                i32x4* bw = (i32x4*)(bs + frow * BK + ((kblk ^ (frow & 7)) * 8));
                *bw = (i32x4){(int)pk2(cv[2*kb].x, cv[2*kb].y),
                              (int)pk2(cv[2*kb].z, cv[2*kb].w),
                              (int)pk2(cv[2*kb+1].x, cv[2*kb+1].y),
                              (int)pk2(cv[2*kb+1].z, cv[2*kb+1].w)};
            }
        }
    };

    auto octet_i = [&](float x) -> i32x4 {
        float e = __builtin_amdgcn_exp2f(fmaf(pc, x, q0));
        float s[NB];
#pragma unroll
        for (int m = 0; m < NB; ++m) {
            s[m] = __builtin_amdgcn_rcpf(1.0f + e);
            e *= R;
        }
        return (i32x4){(int)pk2(s[0], s[1]), (int)pk2(s[2], s[3]),
                       (int)pk2(s[4], s[5]), (int)pk2(s[6], s[7])};
    };

    auto stage_A = [&](float2 xq, short* as_base) {
        short* ap = as_base + arow * LDA + acol * 8;
        *(i32x4*)(ap)     = octet_i(xq.x);
        *(i32x4*)(ap + 8) = octet_i(xq.y);
    };

    // ---- prologue: vm order [x(0), DMA(0) x4, x(1)]; A(0) -> buf0 ----
    float2 xv = *(const float2*)(xp + (size_t)kt0 * NB);
    stage_B(kt0, &Bs[0][0]);
    stage_A(xv, &As[0][0][0]);
    xv = *(const float2*)(xp + (size_t)(kt0 + 1) * NB);
    float2 xn;

    // Per step RT (relative): tiny staging phase issues x(RT+2) + DMA B(RT+1);
    // compute phase does frag reads(CUR), MFMA ks0, stage_A(RT+1)->NXT
    // (interleaves with MFMA on the VALU pipe), MFMA ks1.
#define STEP(RT, CUR, NXT)                                                   \
    {                                                                        \
        const int rn_ = ((RT) + 1 < NKTB) ? (RT) + 1 : NKTB - 1;             \
        const int rx_ = ((RT) + 2 < NKTB) ? (RT) + 2 : NKTB - 1;             \
        xn = *(const float2*)(xp + (size_t)(kt0 + rx_) * NB);                \
        stage_B(kt0 + rn_, &Bs[NXT][0]);                                     \
        asm volatile("s_waitcnt vmcnt(5) lgkmcnt(0)" ::: "memory");          \
        __builtin_amdgcn_s_barrier();                                        \
        const short* abase = &As[CUR][0][0];                                 \
        const short* bbase = &Bs[CUR][0];                                    \
        bf16x8 af[2][2], bfr[2][4];                                          \
        _Pragma("unroll") for (int ks = 0; ks < 2; ++ks) {                   \
            _Pragma("unroll") for (int mf = 0; mf < 2; ++mf)                 \
                af[ks][mf] = *(const bf16x8*)(abase + aoff                   \
                                              + mf * (16 * LDA) + ks * 32);  \
            const int boffk = ks ? boff1 : boff0;                            \
            _Pragma("unroll") for (int nf = 0; nf < 4; ++nf)                 \
                bfr[ks][nf] = *(const bf16x8*)(bbase + boffk                 \
                                               + nf * (16 * BK));            \
        }                                                                    \
        _Pragma("unroll") for (int mf = 0; mf < 2; ++mf)                     \
            _Pragma("unroll") for (int nf = 0; nf < 4; ++nf)                 \
                acc[mf][nf] = __builtin_amdgcn_mfma_f32_16x16x32_bf16(       \
                    af[0][mf], bfr[0][nf], acc[mf][nf], 0, 0, 0);            \
        stage_A(xv, &As[NXT][0][0]);   /* VALU interleaves with MFMAs */     \
        _Pragma("unroll") for (int mf = 0; mf < 2; ++mf)                     \
            _Pragma("unroll") for (int nf = 0; nf < 4; ++nf)                 \
                acc[mf][nf] = __builtin_amdgcn_mfma_f32_16x16x32_bf16(       \
                    af[1][mf], bfr[1][nf], acc[mf][nf], 0, 0, 0);            \
        __builtin_amdgcn_s_barrier();                                        \
        xv = xn;                                                             \
    }

    static_assert(NKTB % 2 == 0, "dbuf unroll");
    for (int t = 0; t < NKTB; t += 2) {
        STEP(t,     0, 1)
        STEP(t + 1, 1, 0)
    }
#undef STEP

    // drain tail staging before LDS dealloc / stores
    asm volatile("s_waitcnt vmcnt(0) lgkmcnt(0)" ::: "memory");

    // ---- epilogue: C/D layout col=lane&15, row=(lane>>4)*4+reg ----
    const int rowb = b0 + wm * 32 + h * 4;
    const int colb = j0 + wn * 64 + rl;
#pragma unroll
    for (int mf = 0; mf < 2; ++mf)
#pragma unroll
        for (int nf = 0; nf < 4; ++nf)
#pragma unroll
            for (int rr = 0; rr < 4; ++rr) {
                const size_t idx = (size_t)(rowb + mf * 16 + rr) * OUTC
                                 + (colb + nf * 16);
                if constexpr (SPLIT)
                    unsafeAtomicAdd(&Y[idx], acc[mf][nf][rr]);  // HW f32 fadd
                else
                    Y[idx] = acc[mf][nf][rr];
            }
}

extern "C" void kernel_launch(void* const* d_in, const int* in_sizes, int n_in,
                              void* d_out, int out_size, void* d_ws, size_t ws_size,
                              hipStream_t stream) {
    const float* X   = (const float*)d_in[0];
    const float* W   = (const float*)d_in[1];
    const float* CEN = (const float*)d_in[2];
    const float* SLP = (const float*)d_in[3];
    float* Y = (float*)d_out;

    static_assert(BATCH % BM == 0 && OUTC % BN == 0 && KDIM % (BK * KSPLIT) == 0,
                  "tiling");

    const size_t WB_BYTES = (size_t)OUTC * KDIM * sizeof(unsigned short); // 4 MB
    if (ws_size >= WB_BYTES) {
        // converts W to bf16 AND zeroes Y for atomic split-K accumulation
        w_prepass<<<dim3((OUTC * KDIM) / (8 * 256)), dim3(256), 0, stream>>>(
            W, (unsigned short*)d_ws, Y);
        dim3 grid(BATCH / BM, OUTC / BN, KSPLIT);   // 128 x 4 x 2 = 1024 blocks
        tanh_basis_fused_gemm<true, true><<<grid, dim3(THREADS), 0, stream>>>(
            X, d_ws, CEN, SLP, Y);
    } else {
        dim3 grid(BATCH / BM, OUTC / BN, 1);        // fallback: no ws, no split
        tanh_basis_fused_gemm<false, false><<<grid, dim3(THREADS), 0, stream>>>(
            X, (const void*)W, CEN, SLP, Y);
    }
}

// Round 8
// 136.902 us; speedup vs baseline: 1.1012x; 1.1012x over previous
//
#include <hip/hip_runtime.h>

#define BATCH 8192
#define INC   512
#define OUTC  512
#define NB    8
#define KDIM  (INC * NB)   // 4096

#define BM 64
#define BN 128
#define BK 64
#define KSPLIT 2
#define THREADS 256
#define LDA 72             // A row stride in shorts (64 + 8 pad), 144 B

typedef __attribute__((ext_vector_type(8))) short bf16x8;
typedef __attribute__((ext_vector_type(4))) float f32x4;
typedef __attribute__((ext_vector_type(4))) int   i32x4;

// truncate-pack two fp32 into two bf16 (lo -> low 16 bits) in one v_perm_b32
static __device__ __forceinline__ unsigned int pk2(float lo, float hi) {
    return __builtin_amdgcn_perm(__builtin_bit_cast(unsigned int, hi),
                                 __builtin_bit_cast(unsigned int, lo),
                                 0x07060302u);
}

// ---- prepass: W fp32 -> bf16 (RNE) into workspace; also zero Y for the
//      split-K atomic accumulation. ----
__global__ __launch_bounds__(256)
void w_prepass(const float* __restrict__ W, unsigned short* __restrict__ Wb,
               float* __restrict__ Y) {
    const int gid  = blockIdx.x * 256 + threadIdx.x;   // 0..262143
    const int base = gid * 8;
    const float4 a = *(const float4*)(W + base);
    const float4 b = *(const float4*)(W + base + 4);
    const float v[8] = {a.x, a.y, a.z, a.w, b.x, b.y, b.z, b.w};
    unsigned int r[8];
#pragma unroll
    for (int i = 0; i < 8; ++i) {
        unsigned int t = __builtin_bit_cast(unsigned int, v[i]);
        t += 0x7FFFu + ((t >> 16) & 1u);   // round-to-nearest-even
        r[i] = t >> 16;
    }
    i32x4 out = {(int)(r[0] | (r[1] << 16)), (int)(r[2] | (r[3] << 16)),
                 (int)(r[4] | (r[5] << 16)), (int)(r[6] | (r[7] << 16))};
    *(i32x4*)(Wb + base) = out;

    float4* yp = (float4*)Y + (size_t)gid * 4;
    const float4 z = {0.f, 0.f, 0.f, 0.f};
#pragma unroll
    for (int i = 0; i < 4; ++i) yp[i] = z;
}

// Round 8 = EXACT R0 structure (the 60us baseline: single-buffered 25.6KB
// LDS, 48 VGPR, syncthreads cadence, proven swizzles) + split-K=2 only.
// Diagnosis across R2..R7: no pipe is ever >40% busy; the kernel is
// LATENCY-bound -- per step each wave runs a serial chain (trans chain ->
// waitcnt -> barrier -> ds_read latency -> MFMA) and at 2 phase-locked
// blocks/CU nothing fills the holes. R0's small footprint fits 4 blocks/CU;
// split-K=2 (grid 1024) delivers them: 16 waves/CU of mutually independent,
// unsynchronized blocks. The syncthreads DMA-drain that R2's counted vmcnt
// optimized is now covered by the other 3 resident blocks.
//
// B LDS layout (swizzled): element (row 0..127, kblk 0..7) at short offset
// row*64 + (kblk ^ (row & 7)) * 8; DMA permutes the GLOBAL k-block.

template <bool DMA, bool SPLIT>
__global__ __launch_bounds__(THREADS, 4)
void tanh_basis_fused_gemm(const float* __restrict__ X,    // (BATCH, INC)
                           const void*  __restrict__ Wsrc, // (OUTC, KDIM)
                           const float* __restrict__ CEN,  // (INC, NB) rows identical
                           const float* __restrict__ SLP,  // (INC, NB) rows identical
                           float* __restrict__ Y)          // (BATCH, OUTC)
{
    __shared__ short As[BM][LDA];     // 9216 B
    __shared__ short Bs[BN * BK];     // 16384 B (swizzled)  -> 25.6 KB total

    const int tid  = threadIdx.x;
    const int lane = tid & 63;
    const int wave = tid >> 6;     // 0..3
    const int wm   = wave & 1;     // m-wave: rows of 32
    const int wn   = wave >> 1;    // n-wave: cols of 64

    const int b0 = blockIdx.x * BM;
    const int j0 = blockIdx.y * BN;
    constexpr int NKTB = SPLIT ? (KDIM / BK / KSPLIT) : (KDIM / BK);  // 32 / 64
    const int kt0 = SPLIT ? blockIdx.z * NKTB : 0;

    // basis: s_m(x) = 1/(1 + exp2(g2*(c_m - x))), g2 = 2*gamma*log2(e)
    const float L2E = 1.4426950408889634f;
    const float g2  = 2.0f * SLP[0] * L2E;
    const float pc  = -g2;
    const float q0  = g2 * CEN[0];
    const float R   = __builtin_amdgcn_exp2f(g2 * (CEN[1] - CEN[0]));

    // A staging role: thread -> (row, 2 consecutive i-slots of the 8-wide slab)
    const int arow = tid >> 2;          // 0..63
    const int acol = (tid & 3) * 2;     // 0,2,4,6
    const float* xp = X + (size_t)(b0 + arow) * INC + acol;
    // x for ABSOLUTE k-tile tt: *(const float2*)(xp + tt*NB)

    f32x4 acc[2][4];
#pragma unroll
    for (int i = 0; i < 2; ++i)
#pragma unroll
        for (int j = 0; j < 4; ++j)
            acc[i][j] = (f32x4){0.f, 0.f, 0.f, 0.f};

    // fragment read base pointers (R0 layout)
    const int rl = lane & 15;
    const int h  = lane >> 4;                        // 0..3
    const short* const arp = &As[wm * 32 + rl][h * 8];
    const int  brow = wn * 64 + rl;
    const int  low3 = lane & 7;                      // == brow & 7
    const short* const brp0 = &Bs[brow * BK + ((h)     ^ low3) * 8]; // ks=0
    const short* const brp1 = &Bs[brow * BK + ((4 + h) ^ low3) * 8]; // ks=1

    // DMA global-side swizzle (per-lane, hoisted out of k-loop)
    const int dma_r    = lane >> 3;                  // row within 8-row chunk
    const int dma_kblk = (lane & 7) ^ dma_r;         // permuted k-block

    float2 xv = *(const float2*)(xp + (size_t)kt0 * NB);   // x for first tile

    for (int rt = 0; rt < NKTB; ++rt) {
        const int ktA = kt0 + rt;

        // ---- issue B staging for this tile ----
        if constexpr (DMA) {
            const unsigned short* Wb = (const unsigned short*)Wsrc;
#pragma unroll
            for (int q = 0; q < 4; ++q) {
                const int cc = wave * 4 + q;   // 1 KB chunk id, wave-uniform
                const unsigned short* gp = Wb
                    + (size_t)(j0 + cc * 8 + dma_r) * KDIM
                    + ktA * BK + dma_kblk * 8;
                __builtin_amdgcn_global_load_lds(
                    (const __attribute__((address_space(1))) void*)gp,
                    (__attribute__((address_space(3))) void*)(Bs + cc * 512),
                    16, 0, 0);
            }
        } else {
            const float* Wf = (const float*)Wsrc;
            const int frow = tid >> 1;     // 0..127
            const int fkh  = tid & 1;      // which 32-float half
            const float* wp = Wf + (size_t)(j0 + frow) * KDIM + ktA * BK + fkh * 32;
            float4 cv[8];
#pragma unroll
            for (int q = 0; q < 8; ++q) cv[q] = ((const float4*)wp)[q];
#pragma unroll
            for (int kb = 0; kb < 4; ++kb) {
                const int kblk = fkh * 4 + kb;
                i32x4* bw = (i32x4*)(Bs + frow * BK + ((kblk ^ (frow & 7)) * 8));
                *bw = (i32x4){(int)pk2(cv[2*kb].x, cv[2*kb].y),
                              (int)pk2(cv[2*kb].z, cv[2*kb].w),
                              (int)pk2(cv[2*kb+1].x, cv[2*kb+1].y),
                              (int)pk2(cv[2*kb+1].z, cv[2*kb+1].w)};
            }
        }

        // ---- prefetch x for next tile ----
        const int rtn = (rt + 1 < NKTB) ? (rt + 1) : (NKTB - 1);
        const float2 xn = *(const float2*)(xp + (size_t)(kt0 + rtn) * NB);

        // ---- compute basis for this tile's A slab, write LDS ----
        {
            float e = __builtin_amdgcn_exp2f(fmaf(pc, xv.x, q0));
            float s[NB];
#pragma unroll
            for (int m = 0; m < NB; ++m) {
                s[m] = __builtin_amdgcn_rcpf(1.0f + e);
                e *= R;
            }
            *(i32x4*)(&As[arow][acol * 8]) =
                (i32x4){(int)pk2(s[0], s[1]), (int)pk2(s[2], s[3]),
                        (int)pk2(s[4], s[5]), (int)pk2(s[6], s[7])};

            e = __builtin_amdgcn_exp2f(fmaf(pc, xv.y, q0));
#pragma unroll
            for (int m = 0; m < NB; ++m) {
                s[m] = __builtin_amdgcn_rcpf(1.0f + e);
                e *= R;
            }
            *(i32x4*)(&As[arow][(acol + 1) * 8]) =
                (i32x4){(int)pk2(s[0], s[1]), (int)pk2(s[2], s[3]),
                        (int)pk2(s[4], s[5]), (int)pk2(s[6], s[7])};
        }

        __syncthreads();   // drains DMA (vmcnt) + ds_writes (lgkm); covered
                           // by the 3 other independent blocks on this CU

        // ---- MFMA on the tile ----
#pragma unroll
        for (int ks = 0; ks < 2; ++ks) {
            const short* brp = ks ? brp1 : brp0;
            bf16x8 af[2], bfr[4];
#pragma unroll
            for (int mf = 0; mf < 2; ++mf)
                af[mf] = *(const bf16x8*)(arp + mf * 16 * LDA + ks * 32);
#pragma unroll
            for (int nf = 0; nf < 4; ++nf)
                bfr[nf] = *(const bf16x8*)(brp + nf * 16 * BK);
#pragma unroll
            for (int mf = 0; mf < 2; ++mf)
#pragma unroll
                for (int nf = 0; nf < 4; ++nf)
                    acc[mf][nf] = __builtin_amdgcn_mfma_f32_16x16x32_bf16(
                        af[mf], bfr[nf], acc[mf][nf], 0, 0, 0);
        }

        __syncthreads();   // reads done before next tile overwrites

        xv = xn;
    }

    // ---- epilogue: C/D layout col=lane&15, row=(lane>>4)*4+reg ----
    const int rowb = b0 + wm * 32 + h * 4;
    const int colb = j0 + wn * 64 + rl;
#pragma unroll
    for (int mf = 0; mf < 2; ++mf)
#pragma unroll
        for (int nf = 0; nf < 4; ++nf)
#pragma unroll
            for (int rr = 0; rr < 4; ++rr) {
                const size_t idx = (size_t)(rowb + mf * 16 + rr) * OUTC
                                 + (colb + nf * 16);
                if constexpr (SPLIT)
                    unsafeAtomicAdd(&Y[idx], acc[mf][nf][rr]);  // HW f32 fadd
                else
                    Y[idx] = acc[mf][nf][rr];
            }
}

extern "C" void kernel_launch(void* const* d_in, const int* in_sizes, int n_in,
                              void* d_out, int out_size, void* d_ws, size_t ws_size,
                              hipStream_t stream) {
    const float* X   = (const float*)d_in[0];
    const float* W   = (const float*)d_in[1];
    const float* CEN = (const float*)d_in[2];
    const float* SLP = (const float*)d_in[3];
    float* Y = (float*)d_out;

    static_assert(BATCH % BM == 0 && OUTC % BN == 0 && KDIM % (BK * KSPLIT) == 0,
                  "tiling");

    const size_t WB_BYTES = (size_t)OUTC * KDIM * sizeof(unsigned short); // 4 MB
    if (ws_size >= WB_BYTES) {
        // converts W to bf16 AND zeroes Y for atomic split-K accumulation
        w_prepass<<<dim3((OUTC * KDIM) / (8 * 256)), dim3(256), 0, stream>>>(
            W, (unsigned short*)d_ws, Y);
        dim3 grid(BATCH / BM, OUTC / BN, KSPLIT);   // 128 x 4 x 2 = 1024 blocks
        tanh_basis_fused_gemm<true, true><<<grid, dim3(THREADS), 0, stream>>>(
            X, d_ws, CEN, SLP, Y);
    } else {
        dim3 grid(BATCH / BM, OUTC / BN, 1);        // fallback: no ws, no split
        tanh_basis_fused_gemm<false, false><<<grid, dim3(THREADS), 0, stream>>>(
            X, (const void*)W, CEN, SLP, Y);
    }
}